// Round 1
// baseline (6383.772 us; speedup 1.0000x reference)
//
#include <hip/hip_runtime.h>
#include <math.h>

#define GRID_F 300
#define EPSF 1e-5f
#define MT 64
#define NT 64
#define GC 32

// ---------------- LayerNorm over 128 (one wave per row) ----------------
__global__ void ln1_kernel(const float* __restrict__ x, const float* __restrict__ w,
                           const float* __restrict__ b, float* __restrict__ xn) {
    int r = blockIdx.x;          // 0..1567
    int t = threadIdx.x;         // 0..63
    const float* row = x + (size_t)r * 128;
    float v0 = row[t], v1 = row[t + 64];
    float s = v0 + v1, q = v0 * v0 + v1 * v1;
    #pragma unroll
    for (int off = 32; off > 0; off >>= 1) {
        s += __shfl_down(s, off);
        q += __shfl_down(q, off);
    }
    s = __shfl(s, 0); q = __shfl(q, 0);
    float mu = s * (1.f / 128.f);
    float var = q * (1.f / 128.f) - mu * mu;
    float rs = rsqrtf(var + EPSF);
    xn[(size_t)r * 128 + t]      = (v0 - mu) * rs * w[t]      + b[t];
    xn[(size_t)r * 128 + t + 64] = (v1 - mu) * rs * w[t + 64] + b[t + 64];
}

// ---------------- LayerNorm over 256 (block=256), input = h1 + fc1_bias ----------------
__global__ void ln2_kernel(const float* __restrict__ h1, const float* __restrict__ bias,
                           const float* __restrict__ w, const float* __restrict__ b,
                           float* __restrict__ h1n) {
    int r = blockIdx.x;          // 0..1567
    int t = threadIdx.x;         // 0..255
    float v = h1[(size_t)r * 256 + t] + bias[t];
    float s = v, q = v * v;
    #pragma unroll
    for (int off = 32; off > 0; off >>= 1) {
        s += __shfl_down(s, off);
        q += __shfl_down(q, off);
    }
    __shared__ float ss[4], qq[4];
    int wid = t >> 6;
    if ((t & 63) == 0) { ss[wid] = s; qq[wid] = q; }
    __syncthreads();
    float S = ss[0] + ss[1] + ss[2] + ss[3];
    float Q = qq[0] + qq[1] + qq[2] + qq[3];
    float mu = S * (1.f / 256.f);
    float var = Q * (1.f / 256.f) - mu * mu;
    float rs = rsqrtf(var + EPSF);
    h1n[(size_t)r * 256 + t] = (v - mu) * rs * w[t] + b[t];
}

// ---------------- fc1: [1568,128] -> [1568,256], K = 128*300*2 ----------------
// grid (4 Ntiles, 25 Mtiles, 8 ksplit over i), block 256
__launch_bounds__(256)
__global__ void fc1_kernel(const float* __restrict__ xn, const float* __restrict__ coeffs,
                           float* __restrict__ h1) {
    const int o0 = blockIdx.x * NT;
    const int m0 = blockIdx.y * MT;
    const int i0 = blockIdx.z * 16;       // 16 i's per block (128/8)
    const int t  = threadIdx.x;

    __shared__ float fbuf[2][MT][GC + 1];
    __shared__ float wbuf[2][NT][GC + 1];
    __shared__ float xrow[MT];

    float acc[4][4] = {};
    const int to = (t & 15) * 4;          // o offset in tile
    const int tm = (t >> 4) * 4;          // m offset in tile

    const float* c0 = coeffs;                               // [256][128][300]
    const float* c1 = coeffs + (size_t)256 * 128 * GRID_F;

    for (int i = i0; i < i0 + 16; ++i) {
        __syncthreads();
        if (t < MT) {
            int mg = m0 + t;
            xrow[t] = (mg < 1568) ? xn[(size_t)mg * 128 + i] : 0.f;
        }
        for (int gc = 0; gc < GRID_F; gc += GC) {
            int gcnt = min(GC, GRID_F - gc);
            __syncthreads();
            // stage features: 64 m x 32 g (cos & sin)
            for (int idx = t; idx < MT * GC; idx += 256) {
                int m = idx >> 5, g = idx & 31;
                float fc_ = 0.f, fs_ = 0.f;
                if (g < gcnt && (m0 + m) < 1568) {
                    float arg = xrow[m] * (float)(gc + g + 1);
                    fc_ = __cosf(arg);
                    fs_ = __sinf(arg);
                }
                fbuf[0][m][g] = fc_;
                fbuf[1][m][g] = fs_;
            }
            // stage weights: 64 o x 32 g x {cos,sin}
            for (int idx = t; idx < NT * GC; idx += 256) {
                int o = idx >> 5, g = idx & 31;
                float w0 = 0.f, w1 = 0.f;
                if (g < gcnt) {
                    size_t base = ((size_t)(o0 + o) * 128 + i) * GRID_F + gc + g;
                    w0 = c0[base];
                    w1 = c1[base];
                }
                wbuf[0][o][g] = w0;
                wbuf[1][o][g] = w1;
            }
            __syncthreads();
            #pragma unroll 4
            for (int g = 0; g < GC; ++g) {
                float fcv[4], fsv[4], w0v[4], w1v[4];
                #pragma unroll
                for (int x = 0; x < 4; ++x) { fcv[x] = fbuf[0][tm + x][g]; fsv[x] = fbuf[1][tm + x][g]; }
                #pragma unroll
                for (int x = 0; x < 4; ++x) { w0v[x] = wbuf[0][to + x][g]; w1v[x] = wbuf[1][to + x][g]; }
                #pragma unroll
                for (int mi = 0; mi < 4; ++mi)
                    #pragma unroll
                    for (int oi = 0; oi < 4; ++oi)
                        acc[mi][oi] += fcv[mi] * w0v[oi] + fsv[mi] * w1v[oi];
            }
        }
    }
    #pragma unroll
    for (int mi = 0; mi < 4; ++mi) {
        int mg = m0 + tm + mi;
        if (mg < 1568) {
            #pragma unroll
            for (int oi = 0; oi < 4; ++oi)
                atomicAdd(&h1[(size_t)mg * 256 + o0 + to + oi], acc[mi][oi]);
        }
    }
}

// ---------------- fc2: rows (b,c) of h1n^T, 196 -> 196, K = 196*300*2 ----------------
// grid (4 Ntiles, 32 Mtiles, 4 ksplit over i), block 256
__launch_bounds__(256)
__global__ void fc2_kernel(const float* __restrict__ h1n, const float* __restrict__ coeffs,
                           float* __restrict__ out) {
    const int o0 = blockIdx.x * NT;       // output n index (guard < 196)
    const int m0 = blockIdx.y * MT;       // row = b*256 + c ; MT=64 divides 256
    const int b  = m0 >> 8;
    const int cb = m0 & 255;
    const int i0 = blockIdx.z * 49;       // 196/4
    const int t  = threadIdx.x;

    __shared__ float fbuf[2][MT][GC + 1];
    __shared__ float wbuf[2][NT][GC + 1];
    __shared__ float xrow[MT];

    float acc[4][4] = {};
    const int to = (t & 15) * 4;
    const int tm = (t >> 4) * 4;

    const float* d0 = coeffs;                               // [196][196][300]
    const float* d1 = coeffs + (size_t)196 * 196 * GRID_F;

    for (int i = i0; i < i0 + 49; ++i) {
        __syncthreads();
        if (t < MT) {
            // transpose read: z[b, c, i] = h1n[(b*196 + i)*256 + c] -- coalesced in c
            xrow[t] = h1n[((size_t)b * 196 + i) * 256 + cb + t];
        }
        for (int gc = 0; gc < GRID_F; gc += GC) {
            int gcnt = min(GC, GRID_F - gc);
            __syncthreads();
            for (int idx = t; idx < MT * GC; idx += 256) {
                int m = idx >> 5, g = idx & 31;
                float fc_ = 0.f, fs_ = 0.f;
                if (g < gcnt) {
                    float arg = xrow[m] * (float)(gc + g + 1);
                    fc_ = __cosf(arg);
                    fs_ = __sinf(arg);
                }
                fbuf[0][m][g] = fc_;
                fbuf[1][m][g] = fs_;
            }
            for (int idx = t; idx < NT * GC; idx += 256) {
                int o = idx >> 5, g = idx & 31;
                float w0 = 0.f, w1 = 0.f;
                if (g < gcnt && (o0 + o) < 196) {
                    size_t base = ((size_t)(o0 + o) * 196 + i) * GRID_F + gc + g;
                    w0 = d0[base];
                    w1 = d1[base];
                }
                wbuf[0][o][g] = w0;
                wbuf[1][o][g] = w1;
            }
            __syncthreads();
            #pragma unroll 4
            for (int g = 0; g < GC; ++g) {
                float fcv[4], fsv[4], w0v[4], w1v[4];
                #pragma unroll
                for (int x = 0; x < 4; ++x) { fcv[x] = fbuf[0][tm + x][g]; fsv[x] = fbuf[1][tm + x][g]; }
                #pragma unroll
                for (int x = 0; x < 4; ++x) { w0v[x] = wbuf[0][to + x][g]; w1v[x] = wbuf[1][to + x][g]; }
                #pragma unroll
                for (int mi = 0; mi < 4; ++mi)
                    #pragma unroll
                    for (int oi = 0; oi < 4; ++oi)
                        acc[mi][oi] += fcv[mi] * w0v[oi] + fsv[mi] * w1v[oi];
            }
        }
    }
    #pragma unroll
    for (int oi = 0; oi < 4; ++oi) {
        int og = o0 + to + oi;
        if (og < 196) {
            #pragma unroll
            for (int mi = 0; mi < 4; ++mi) {
                // out[b, og, c] with c = cb + tm + mi
                atomicAdd(&out[((size_t)b * 196 + og) * 256 + cb + tm + mi], acc[oi][oi == oi ? mi : mi] * 0.f + acc[mi][oi]);
            }
        }
    }
}

// ---------------- fc2 bias epilogue: out[b, n, c] += bias[n] ----------------
__global__ void bias2_kernel(float* __restrict__ out, const float* __restrict__ bias) {
    int idx = blockIdx.x * 256 + threadIdx.x;   // < 401408
    int n = (idx >> 8) % 196;
    out[idx] += bias[n];
}

extern "C" void kernel_launch(void* const* d_in, const int* in_sizes, int n_in,
                              void* d_out, int out_size, void* d_ws, size_t ws_size,
                              hipStream_t stream) {
    const float* x       = (const float*)d_in[0];   // [8,196,128]
    const float* ln1w    = (const float*)d_in[1];   // [128]
    const float* ln1b    = (const float*)d_in[2];   // [128]
    const float* fc1c    = (const float*)d_in[3];   // [2,256,128,300]
    const float* fc1bias = (const float*)d_in[4];   // [1,256]
    const float* ln2w    = (const float*)d_in[5];   // [256]
    const float* ln2b    = (const float*)d_in[6];   // [256]
    const float* fc2c    = (const float*)d_in[7];   // [2,196,196,300]
    const float* fc2bias = (const float*)d_in[8];   // [1,196]
    float* out = (float*)d_out;                     // [8,196,256] flat (== [8,392,128])

    float* xn  = (float*)d_ws;          // 1568*128
    float* h1  = xn + 200704;           // 1568*256
    float* h1n = h1 + 401408;           // 1568*256

    hipMemsetAsync(h1, 0, (size_t)401408 * 4, stream);
    hipMemsetAsync(d_out, 0, (size_t)401408 * 4, stream);

    ln1_kernel<<<1568, 64, 0, stream>>>(x, ln1w, ln1b, xn);
    fc1_kernel<<<dim3(4, 25, 8), 256, 0, stream>>>(xn, fc1c, h1);
    ln2_kernel<<<1568, 256, 0, stream>>>(h1, fc1bias, ln2w, ln2b, h1n);
    fc2_kernel<<<dim3(4, 32, 4), 256, 0, stream>>>(h1n, fc2c, out);
    bias2_kernel<<<1568, 256, 0, stream>>>(out, fc2bias);
}

// Round 3
// 1223.930 us; speedup vs baseline: 5.2158x; 5.2158x over previous
//
#include <hip/hip_runtime.h>
#include <math.h>

typedef short short8 __attribute__((ext_vector_type(8)));
typedef float f32x4 __attribute__((ext_vector_type(4)));

#define EPSF 1e-5f

union FragU {
    uint4 q;
    unsigned u[4];
    short8 v;
};

// bf16 round-to-nearest-even, manual (avoids __hip_bfloat162 bit_cast issue)
__device__ __forceinline__ unsigned bf16_rne(float f) {
    unsigned u = __float_as_uint(f);
    unsigned r = u + 0x7FFFu + ((u >> 16) & 1u);
    return r >> 16;
}
__device__ __forceinline__ unsigned pack_bf2(float a, float b) {
    return bf16_rne(a) | (bf16_rne(b) << 16);
}
// reconstruct the fp32 value that each packed bf16 half represents
__device__ __forceinline__ float bf_lo_f32(unsigned w) { return __uint_as_float(w << 16); }
__device__ __forceinline__ float bf_hi_f32(unsigned w) { return __uint_as_float(w & 0xFFFF0000u); }

// ---------------- LN over 128, writes TRANSPOSED xnT[i][m] (m padded to 1792) ----------------
__global__ void ln1_kernel(const float* __restrict__ x, const float* __restrict__ w,
                           const float* __restrict__ b, float* __restrict__ xnT) {
    int r = blockIdx.x;          // 0..1567
    int t = threadIdx.x;         // 0..63
    const float* row = x + (size_t)r * 128;
    float v0 = row[t], v1 = row[t + 64];
    float s = v0 + v1, q = v0 * v0 + v1 * v1;
    #pragma unroll
    for (int off = 32; off > 0; off >>= 1) {
        s += __shfl_down(s, off);
        q += __shfl_down(q, off);
    }
    s = __shfl(s, 0); q = __shfl(q, 0);
    float mu = s * (1.f / 128.f);
    float var = q * (1.f / 128.f) - mu * mu;
    float rs = rsqrtf(var + EPSF);
    xnT[(size_t)t * 1792 + r]        = (v0 - mu) * rs * w[t]      + b[t];
    xnT[(size_t)(t + 64) * 1792 + r] = (v1 - mu) * rs * w[t + 64] + b[t + 64];
}

// ---------------- fc1: split-bf16 MFMA GEMM. M=1792(pad), N=256, K=128*608 ----------------
// grid (2 ntiles, 7 mtiles, ks1), block 512 (8 waves). Wave: m=32 (2 frags), n=128 (8 frags).
__launch_bounds__(512)
__global__ void fc1_kernel(const float* __restrict__ xnT, const float* __restrict__ coeffs,
                           float* __restrict__ part1, int KS) {
    const int nt = blockIdx.x;
    const int mt = blockIdx.y;
    const int ks = blockIdx.z;
    const int i0 = (ks * 128) / KS, i1 = ((ks + 1) * 128) / KS;
    const int t = threadIdx.x;
    const int wv = t >> 6, ln = t & 63;
    const int q = ln >> 4, col = ln & 15;
    const int mrow = mt * 256 + wv * 32;

    __shared__ unsigned bhi[128 * 36];
    __shared__ unsigned blo[128 * 36];

    const float* c0 = coeffs;                                   // [256][128][300]
    const float* c1 = coeffs + (size_t)256 * 128 * 300;

    f32x4 acc[2][8] = {};

    const int o_loc = t >> 2, qu = t & 3;    // staging role
    const int og = nt * 128 + o_loc;

    for (int i = i0; i < i1; ++i) {
        const int mg0 = mrow + col, mg1 = mrow + 16 + col;
        const float zu0 = (mg0 < 1568) ? xnT[(size_t)i * 1792 + mg0] : 0.f;
        const float zu1 = (mg1 < 1568) ? xnT[(size_t)i * 1792 + mg1] : 0.f;
        const float* p0 = c0 + ((size_t)og * 128 + i) * 300;
        const float* p1 = c1 + ((size_t)og * 128 + i) * 300;

        for (int c = 0; c < 10; ++c) {       // k-chunks of 64 (32 g-pairs)
            __syncthreads();
            {
                unsigned hw[8], lw[8];
                #pragma unroll
                for (int pp = 0; pp < 8; ++pp) {
                    int g = c * 32 + qu * 8 + pp;
                    float w0 = 0.f, w1 = 0.f;
                    if (g < 300) { w0 = p0[g]; w1 = p1[g]; }
                    unsigned h_ = pack_bf2(w0, w1);
                    hw[pp] = h_;
                    lw[pp] = pack_bf2(w0 - bf_lo_f32(h_), w1 - bf_hi_f32(h_));
                }
                int base = o_loc * 36 + qu * 8;
                *(uint4*)&bhi[base]     = make_uint4(hw[0], hw[1], hw[2], hw[3]);
                *(uint4*)&bhi[base + 4] = make_uint4(hw[4], hw[5], hw[6], hw[7]);
                *(uint4*)&blo[base]     = make_uint4(lw[0], lw[1], lw[2], lw[3]);
                *(uint4*)&blo[base + 4] = make_uint4(lw[4], lw[5], lw[6], lw[7]);
            }
            __syncthreads();
            #pragma unroll
            for (int h = 0; h < 2; ++h) {
                FragU ah0, al0, ah1, al1;
                int g0 = c * 32 + h * 16 + q * 4;
                #pragma unroll
                for (int d = 0; d < 4; ++d) {
                    float kf = (float)(g0 + d + 1);
                    float a0 = zu0 * kf, a1 = zu1 * kf;
                    float cv0 = __cosf(a0), sv0 = __sinf(a0);
                    float cv1 = __cosf(a1), sv1 = __sinf(a1);
                    unsigned h0 = pack_bf2(cv0, sv0);
                    unsigned h1_ = pack_bf2(cv1, sv1);
                    ah0.u[d] = h0;  al0.u[d] = pack_bf2(cv0 - bf_lo_f32(h0), sv0 - bf_hi_f32(h0));
                    ah1.u[d] = h1_; al1.u[d] = pack_bf2(cv1 - bf_lo_f32(h1_), sv1 - bf_hi_f32(h1_));
                }
                #pragma unroll
                for (int un = 0; un < 8; ++un) {
                    int row = un * 16 + col;
                    FragU bh, bl;
                    bh.q = *(const uint4*)&bhi[row * 36 + h * 16 + q * 4];
                    bl.q = *(const uint4*)&blo[row * 36 + h * 16 + q * 4];
                    acc[0][un] = __builtin_amdgcn_mfma_f32_16x16x32_bf16(ah0.v, bh.v, acc[0][un], 0, 0, 0);
                    acc[0][un] = __builtin_amdgcn_mfma_f32_16x16x32_bf16(ah0.v, bl.v, acc[0][un], 0, 0, 0);
                    acc[0][un] = __builtin_amdgcn_mfma_f32_16x16x32_bf16(al0.v, bh.v, acc[0][un], 0, 0, 0);
                    acc[1][un] = __builtin_amdgcn_mfma_f32_16x16x32_bf16(ah1.v, bh.v, acc[1][un], 0, 0, 0);
                    acc[1][un] = __builtin_amdgcn_mfma_f32_16x16x32_bf16(ah1.v, bl.v, acc[1][un], 0, 0, 0);
                    acc[1][un] = __builtin_amdgcn_mfma_f32_16x16x32_bf16(al1.v, bh.v, acc[1][un], 0, 0, 0);
                }
            }
        }
    }
    #pragma unroll
    for (int um = 0; um < 2; ++um) {
        int mbase = mrow + um * 16 + q * 4;
        #pragma unroll
        for (int un = 0; un < 8; ++un) {
            int o = nt * 128 + un * 16 + col;
            #pragma unroll
            for (int r = 0; r < 4; ++r)
                part1[((size_t)ks * 1792 + mbase + r) * 256 + o] = acc[um][un][r];
        }
    }
}

// ---------------- reduce ks1 planes + fc1_bias, then LN over 256 -> h1n ----------------
__global__ void reduce1_ln2(const float* __restrict__ part1, const float* __restrict__ bias,
                            const float* __restrict__ w, const float* __restrict__ b,
                            float* __restrict__ h1n, int KS) {
    int r = blockIdx.x;          // 0..1567
    int t = threadIdx.x;         // 0..255
    float v = bias[t];
    for (int ks = 0; ks < KS; ++ks) v += part1[((size_t)ks * 1792 + r) * 256 + t];
    float s = v, q = v * v;
    #pragma unroll
    for (int off = 32; off > 0; off >>= 1) {
        s += __shfl_down(s, off);
        q += __shfl_down(q, off);
    }
    __shared__ float ss[4], qq[4];
    int wid = t >> 6;
    if ((t & 63) == 0) { ss[wid] = s; qq[wid] = q; }
    __syncthreads();
    float S = ss[0] + ss[1] + ss[2] + ss[3];
    float Q = qq[0] + qq[1] + qq[2] + qq[3];
    float mu = S * (1.f / 256.f);
    float var = Q * (1.f / 256.f) - mu * mu;
    float rs = rsqrtf(var + EPSF);
    h1n[(size_t)r * 256 + t] = (v - mu) * rs * w[t] + b[t];
}

// ---------------- fc2: bf16 MFMA GEMM. M=2048 (b*256+c), N=224(pad of 196), K=196*608 ----------------
// grid (2 ntiles, 8 b, ks2), block 512 (8 waves). Wave: m=32 (2 frags), n=112 (7 frags).
__launch_bounds__(512)
__global__ void fc2_kernel(const float* __restrict__ h1n, const float* __restrict__ coeffs,
                           float* __restrict__ part2, int KS) {
    const int nt = blockIdx.x;
    const int bb = blockIdx.y;           // batch == m-tile of 256
    const int ks = blockIdx.z;
    const int i0 = (ks * 196) / KS, i1 = ((ks + 1) * 196) / KS;
    const int t = threadIdx.x;
    const int wv = t >> 6, ln = t & 63;
    const int q = ln >> 4, col = ln & 15;
    const int crow = wv * 32;            // wave's first c

    __shared__ unsigned bs[112 * 36];

    const float* c0 = coeffs;                                   // [196][196][300]
    const float* c1 = coeffs + (size_t)196 * 196 * 300;

    f32x4 acc[2][7] = {};

    const int o_loc = t >> 2, qu = t & 3;    // staging role (t<448 active)
    const int og = nt * 112 + o_loc;
    const bool stage_on = (t < 448) && (og < 196);

    for (int i = i0; i < i1; ++i) {
        const float zu0 = h1n[((size_t)bb * 196 + i) * 256 + crow + col];
        const float zu1 = h1n[((size_t)bb * 196 + i) * 256 + crow + 16 + col];
        const float* p0 = c0 + ((size_t)og * 196 + i) * 300;
        const float* p1 = c1 + ((size_t)og * 196 + i) * 300;

        for (int c = 0; c < 10; ++c) {
            __syncthreads();
            if (t < 448) {
                unsigned hw[8];
                #pragma unroll
                for (int pp = 0; pp < 8; ++pp) {
                    int g = c * 32 + qu * 8 + pp;
                    float w0 = 0.f, w1 = 0.f;
                    if (stage_on && g < 300) { w0 = p0[g]; w1 = p1[g]; }
                    hw[pp] = pack_bf2(w0, w1);
                }
                int base = o_loc * 36 + qu * 8;
                *(uint4*)&bs[base]     = make_uint4(hw[0], hw[1], hw[2], hw[3]);
                *(uint4*)&bs[base + 4] = make_uint4(hw[4], hw[5], hw[6], hw[7]);
            }
            __syncthreads();
            #pragma unroll
            for (int h = 0; h < 2; ++h) {
                FragU a0, a1;
                int g0 = c * 32 + h * 16 + q * 4;
                #pragma unroll
                for (int d = 0; d < 4; ++d) {
                    float kf = (float)(g0 + d + 1);
                    float aa0 = zu0 * kf, aa1 = zu1 * kf;
                    a0.u[d] = pack_bf2(__cosf(aa0), __sinf(aa0));
                    a1.u[d] = pack_bf2(__cosf(aa1), __sinf(aa1));
                }
                #pragma unroll
                for (int un = 0; un < 7; ++un) {
                    int row = un * 16 + col;
                    FragU bh;
                    bh.q = *(const uint4*)&bs[row * 36 + h * 16 + q * 4];
                    acc[0][un] = __builtin_amdgcn_mfma_f32_16x16x32_bf16(a0.v, bh.v, acc[0][un], 0, 0, 0);
                    acc[1][un] = __builtin_amdgcn_mfma_f32_16x16x32_bf16(a1.v, bh.v, acc[1][un], 0, 0, 0);
                }
            }
        }
    }
    #pragma unroll
    for (int um = 0; um < 2; ++um) {
        int mbase = bb * 256 + crow + um * 16 + q * 4;
        #pragma unroll
        for (int un = 0; un < 7; ++un) {
            int o = nt * 112 + un * 16 + col;
            #pragma unroll
            for (int r = 0; r < 4; ++r)
                part2[((size_t)ks * 2048 + mbase + r) * 224 + o] = acc[um][un][r];
        }
    }
}

// ---------------- reduce ks2 planes + fc2_bias -> out[b][o][c] ----------------
__global__ void reduce2_kernel(const float* __restrict__ part2, const float* __restrict__ bias,
                               float* __restrict__ out, int KS) {
    int ot = blockIdx.x;         // 0..12 (o tile of 16)
    int b  = blockIdx.y;         // 0..7
    int t  = threadIdx.x;        // c = 0..255
    float s[16] = {};
    for (int ks = 0; ks < KS; ++ks) {
        const float* p = part2 + ((size_t)ks * 2048 + b * 256 + t) * 224 + ot * 16;
        #pragma unroll
        for (int j4 = 0; j4 < 4; ++j4) {
            float4 a = *(const float4*)(p + j4 * 4);
            s[j4 * 4 + 0] += a.x; s[j4 * 4 + 1] += a.y;
            s[j4 * 4 + 2] += a.z; s[j4 * 4 + 3] += a.w;
        }
    }
    #pragma unroll
    for (int j = 0; j < 16; ++j) {
        int o = ot * 16 + j;
        if (o < 196)
            out[((size_t)b * 196 + o) * 256 + t] = s[j] + bias[o];
    }
}

extern "C" void kernel_launch(void* const* d_in, const int* in_sizes, int n_in,
                              void* d_out, int out_size, void* d_ws, size_t ws_size,
                              hipStream_t stream) {
    const float* x       = (const float*)d_in[0];   // [8,196,128]
    const float* ln1w    = (const float*)d_in[1];
    const float* ln1b    = (const float*)d_in[2];
    const float* fc1c    = (const float*)d_in[3];   // [2,256,128,300]
    const float* fc1bias = (const float*)d_in[4];   // [1,256]
    const float* ln2w    = (const float*)d_in[5];
    const float* ln2b    = (const float*)d_in[6];
    const float* fc2c    = (const float*)d_in[7];   // [2,196,196,300]
    const float* fc2bias = (const float*)d_in[8];   // [1,196]
    float* out = (float*)d_out;                     // [8,196,256] flat

    // workspace layout (floats)
    const size_t xnT_elems = (size_t)128 * 1792;    // 229376
    const size_t h1n_elems = 401408;
    const size_t plane     = 458752;                // 1792*256 == 2048*224
    const size_t fixedB    = (xnT_elems + h1n_elems) * 4;

    int ks1 = 18, ks2 = 16;
    {
        long long planes = (ws_size > fixedB) ? (long long)((ws_size - fixedB) / (plane * 4)) : 2;
        if (planes < 2) planes = 2;
        if (planes < 34) {
            ks2 = (int)(planes / 2);
            ks1 = (int)(planes - ks2);
            if (ks2 < 1) ks2 = 1;
            if (ks1 < 1) ks1 = 1;
            if (ks1 > 18) ks1 = 18;
            if (ks2 > 16) ks2 = 16;
        }
    }

    float* xnT   = (float*)d_ws;
    float* h1n   = xnT + xnT_elems;
    float* part1 = h1n + h1n_elems;
    float* part2 = part1 + (size_t)ks1 * plane;

    ln1_kernel<<<1568, 64, 0, stream>>>(x, ln1w, ln1b, xnT);
    fc1_kernel<<<dim3(2, 7, ks1), 512, 0, stream>>>(xnT, fc1c, part1, ks1);
    reduce1_ln2<<<1568, 256, 0, stream>>>(part1, fc1bias, ln2w, ln2b, h1n, ks1);
    fc2_kernel<<<dim3(2, 8, ks2), 512, 0, stream>>>(h1n, fc2c, part2, ks2);
    reduce2_kernel<<<dim3(13, 8), 256, 0, stream>>>(part2, fc2bias, out, ks2);
}

// Round 4
// 865.485 us; speedup vs baseline: 7.3759x; 1.4142x over previous
//
#include <hip/hip_runtime.h>
#include <math.h>

typedef short short8 __attribute__((ext_vector_type(8)));
typedef float f32x4 __attribute__((ext_vector_type(4)));

#define EPSF 1e-5f

union FragU {
    uint4 q;
    unsigned u[4];
    short8 v;
};

// --- bf16 truncation packing via v_perm_b32 ---
// returns (bf16_trunc(hi_val) << 16) | bf16_trunc(lo_val)  -- 1 instruction
__device__ __forceinline__ unsigned pack_trunc2(float lo_val, float hi_val) {
    return __builtin_amdgcn_perm(__float_as_uint(hi_val), __float_as_uint(lo_val), 0x07060302u);
}
// fp32 value of the bf16-truncation of x
__device__ __forceinline__ float trunc_bf(float x) {
    return __uint_as_float(__float_as_uint(x) & 0xFFFF0000u);
}

// ---------------- LN over 128, writes TRANSPOSED xnT[i][m] (m padded to 1792) ----------------
__global__ void ln1_kernel(const float* __restrict__ x, const float* __restrict__ w,
                           const float* __restrict__ b, float* __restrict__ xnT) {
    int r = blockIdx.x;          // 0..1567
    int t = threadIdx.x;         // 0..63
    const float* row = x + (size_t)r * 128;
    float v0 = row[t], v1 = row[t + 64];
    float s = v0 + v1, q = v0 * v0 + v1 * v1;
    #pragma unroll
    for (int off = 32; off > 0; off >>= 1) {
        s += __shfl_down(s, off);
        q += __shfl_down(q, off);
    }
    s = __shfl(s, 0); q = __shfl(q, 0);
    float mu = s * (1.f / 128.f);
    float var = q * (1.f / 128.f) - mu * mu;
    float rs = rsqrtf(var + EPSF);
    xnT[(size_t)t * 1792 + r]        = (v0 - mu) * rs * w[t]      + b[t];
    xnT[(size_t)(t + 64) * 1792 + r] = (v1 - mu) * rs * w[t + 64] + b[t + 64];
}

// ---------------- fc1: split-bf16 MFMA GEMM. M=1792(pad), N=256, K=128*608 ----------------
// grid (2 ntiles, 14 mtiles of 128, ks1=16), block 256 (4 waves). Wave: m=32, n=128.
__launch_bounds__(256)
__global__ void fc1_kernel(const float* __restrict__ xnT, const float* __restrict__ coeffs,
                           float* __restrict__ part1, int KS) {
    const int nt = blockIdx.x;
    const int mt = blockIdx.y;
    const int ks = blockIdx.z;
    const int i0 = (ks * 128) / KS, i1 = ((ks + 1) * 128) / KS;
    const int t = threadIdx.x;
    const int wv = t >> 6, ln = t & 63;
    const int q = ln >> 4, col = ln & 15;
    const int mrow = mt * 128 + wv * 32;

    __shared__ unsigned bhi[128 * 36];
    __shared__ unsigned blo[128 * 36];

    const float* c0 = coeffs;                                   // [256][128][300]
    const float* c1 = coeffs + (size_t)256 * 128 * 300;

    f32x4 acc[2][8] = {};

    // staging role: thread -> (row o_loc, 16 g-slots starting at j0)
    const int o_loc = t >> 1;
    const int j0 = (t & 1) * 16;
    const int og = nt * 128 + o_loc;

    for (int i = i0; i < i1; ++i) {
        const int mg0 = mrow + col, mg1 = mrow + 16 + col;
        const float zu0 = (mg0 < 1568) ? xnT[(size_t)i * 1792 + mg0] : 0.f;
        const float zu1 = (mg1 < 1568) ? xnT[(size_t)i * 1792 + mg1] : 0.f;
        const float* p0 = c0 + ((size_t)og * 128 + i) * 300;
        const float* p1 = c1 + ((size_t)og * 128 + i) * 300;

        for (int c = 0; c < 10; ++c) {       // k-chunks of 64 (32 g-pairs)
            __syncthreads();
            #pragma unroll
            for (int half = 0; half < 2; ++half) {
                int gbase = c * 32 + j0 + half * 8;
                float w0[8], w1[8];
                #pragma unroll
                for (int k4 = 0; k4 < 2; ++k4) {
                    int g = gbase + k4 * 4;
                    if (g + 4 <= 300) {
                        float4 a = *(const float4*)(p0 + g);
                        float4 bb = *(const float4*)(p1 + g);
                        w0[k4*4+0] = a.x;  w0[k4*4+1] = a.y;  w0[k4*4+2] = a.z;  w0[k4*4+3] = a.w;
                        w1[k4*4+0] = bb.x; w1[k4*4+1] = bb.y; w1[k4*4+2] = bb.z; w1[k4*4+3] = bb.w;
                    } else {
                        #pragma unroll
                        for (int e = 0; e < 4; ++e) {
                            int gg = g + e;
                            w0[k4*4+e] = (gg < 300) ? p0[gg] : 0.f;
                            w1[k4*4+e] = (gg < 300) ? p1[gg] : 0.f;
                        }
                    }
                }
                unsigned hw[8], lw[8];
                #pragma unroll
                for (int k = 0; k < 8; ++k) {
                    hw[k] = pack_trunc2(w0[k], w1[k]);
                    lw[k] = pack_trunc2(w0[k] - trunc_bf(w0[k]), w1[k] - trunc_bf(w1[k]));
                }
                int base = o_loc * 36 + j0 + half * 8;
                *(uint4*)&bhi[base]     = make_uint4(hw[0], hw[1], hw[2], hw[3]);
                *(uint4*)&bhi[base + 4] = make_uint4(hw[4], hw[5], hw[6], hw[7]);
                *(uint4*)&blo[base]     = make_uint4(lw[0], lw[1], lw[2], lw[3]);
                *(uint4*)&blo[base + 4] = make_uint4(lw[4], lw[5], lw[6], lw[7]);
            }
            __syncthreads();
            #pragma unroll
            for (int h = 0; h < 2; ++h) {
                FragU ah0, al0, ah1, al1;
                int g0 = c * 32 + h * 16 + q * 4;
                #pragma unroll
                for (int d = 0; d < 4; ++d) {
                    float kf = (float)(g0 + d + 1);
                    float a0 = zu0 * kf, a1 = zu1 * kf;
                    float cv0 = __cosf(a0), sv0 = __sinf(a0);
                    float cv1 = __cosf(a1), sv1 = __sinf(a1);
                    ah0.u[d] = pack_trunc2(cv0, sv0);
                    al0.u[d] = pack_trunc2(cv0 - trunc_bf(cv0), sv0 - trunc_bf(sv0));
                    ah1.u[d] = pack_trunc2(cv1, sv1);
                    al1.u[d] = pack_trunc2(cv1 - trunc_bf(cv1), sv1 - trunc_bf(sv1));
                }
                #pragma unroll
                for (int un = 0; un < 8; ++un) {
                    int row = un * 16 + col;
                    FragU bh, bl;
                    bh.q = *(const uint4*)&bhi[row * 36 + h * 16 + q * 4];
                    bl.q = *(const uint4*)&blo[row * 36 + h * 16 + q * 4];
                    acc[0][un] = __builtin_amdgcn_mfma_f32_16x16x32_bf16(ah0.v, bh.v, acc[0][un], 0, 0, 0);
                    acc[0][un] = __builtin_amdgcn_mfma_f32_16x16x32_bf16(ah0.v, bl.v, acc[0][un], 0, 0, 0);
                    acc[0][un] = __builtin_amdgcn_mfma_f32_16x16x32_bf16(al0.v, bh.v, acc[0][un], 0, 0, 0);
                    acc[1][un] = __builtin_amdgcn_mfma_f32_16x16x32_bf16(ah1.v, bh.v, acc[1][un], 0, 0, 0);
                    acc[1][un] = __builtin_amdgcn_mfma_f32_16x16x32_bf16(ah1.v, bl.v, acc[1][un], 0, 0, 0);
                    acc[1][un] = __builtin_amdgcn_mfma_f32_16x16x32_bf16(al1.v, bh.v, acc[1][un], 0, 0, 0);
                }
            }
        }
    }
    #pragma unroll
    for (int um = 0; um < 2; ++um) {
        int mbase = mrow + um * 16 + q * 4;
        #pragma unroll
        for (int un = 0; un < 8; ++un) {
            int o = nt * 128 + un * 16 + col;
            #pragma unroll
            for (int r = 0; r < 4; ++r)
                part1[((size_t)ks * 1792 + mbase + r) * 256 + o] = acc[um][un][r];
        }
    }
}

// ---------------- reduce ks1 planes + fc1_bias, then LN over 256 -> h1n ----------------
__global__ void reduce1_ln2(const float* __restrict__ part1, const float* __restrict__ bias,
                            const float* __restrict__ w, const float* __restrict__ b,
                            float* __restrict__ h1n, int KS) {
    int r = blockIdx.x;          // 0..1567
    int t = threadIdx.x;         // 0..255
    float v = bias[t];
    for (int ks = 0; ks < KS; ++ks) v += part1[((size_t)ks * 1792 + r) * 256 + t];
    float s = v, q = v * v;
    #pragma unroll
    for (int off = 32; off > 0; off >>= 1) {
        s += __shfl_down(s, off);
        q += __shfl_down(q, off);
    }
    __shared__ float ss[4], qq[4];
    int wid = t >> 6;
    if ((t & 63) == 0) { ss[wid] = s; qq[wid] = q; }
    __syncthreads();
    float S = ss[0] + ss[1] + ss[2] + ss[3];
    float Q = qq[0] + qq[1] + qq[2] + qq[3];
    float mu = S * (1.f / 256.f);
    float var = Q * (1.f / 256.f) - mu * mu;
    float rs = rsqrtf(var + EPSF);
    h1n[(size_t)r * 256 + t] = (v - mu) * rs * w[t] + b[t];
}

// ---------------- fc2: bf16 MFMA GEMM. M=2048 (b*256+c), N=224(pad of 196), K=196*608 ----------------
// grid (2 ntiles, 16 mtiles of 128, ks2=14), block 256 (4 waves). Wave: m=32, n=112.
__launch_bounds__(256)
__global__ void fc2_kernel(const float* __restrict__ h1n, const float* __restrict__ coeffs,
                           float* __restrict__ part2, int KS) {
    const int nt = blockIdx.x;
    const int mt = blockIdx.y;           // 0..15 : b = mt>>1, c-base = (mt&1)*128
    const int ks = blockIdx.z;
    const int i0 = (ks * 196) / KS, i1 = ((ks + 1) * 196) / KS;
    const int t = threadIdx.x;
    const int wv = t >> 6, ln = t & 63;
    const int q = ln >> 4, col = ln & 15;
    const int b = mt >> 1;
    const int cb = (mt & 1) * 128 + wv * 32;   // wave's first c

    __shared__ unsigned bs[112 * 36];

    const float* c0 = coeffs;                                   // [196][196][300]
    const float* c1 = coeffs + (size_t)196 * 196 * 300;

    f32x4 acc[2][7] = {};

    // staging role (t<224): row o_loc, 16 g-slots starting at j0
    const int o_loc = t >> 1;
    const int j0 = (t & 1) * 16;
    const int og = nt * 112 + o_loc;
    const bool stage_on = (t < 224) && (og < 196);

    for (int i = i0; i < i1; ++i) {
        const float zu0 = h1n[((size_t)b * 196 + i) * 256 + cb + col];
        const float zu1 = h1n[((size_t)b * 196 + i) * 256 + cb + 16 + col];
        const float* p0 = c0 + ((size_t)og * 196 + i) * 300;
        const float* p1 = c1 + ((size_t)og * 196 + i) * 300;

        for (int c = 0; c < 10; ++c) {
            __syncthreads();
            if (t < 224) {
                #pragma unroll
                for (int half = 0; half < 2; ++half) {
                    int gbase = c * 32 + j0 + half * 8;
                    float w0[8], w1[8];
                    #pragma unroll
                    for (int k4 = 0; k4 < 2; ++k4) {
                        int g = gbase + k4 * 4;
                        if (stage_on && g + 4 <= 300) {
                            float4 a = *(const float4*)(p0 + g);
                            float4 bb = *(const float4*)(p1 + g);
                            w0[k4*4+0] = a.x;  w0[k4*4+1] = a.y;  w0[k4*4+2] = a.z;  w0[k4*4+3] = a.w;
                            w1[k4*4+0] = bb.x; w1[k4*4+1] = bb.y; w1[k4*4+2] = bb.z; w1[k4*4+3] = bb.w;
                        } else {
                            #pragma unroll
                            for (int e = 0; e < 4; ++e) {
                                int gg = g + e;
                                bool ok = stage_on && (gg < 300);
                                w0[k4*4+e] = ok ? p0[gg] : 0.f;
                                w1[k4*4+e] = ok ? p1[gg] : 0.f;
                            }
                        }
                    }
                    unsigned hw[8];
                    #pragma unroll
                    for (int k = 0; k < 8; ++k) hw[k] = pack_trunc2(w0[k], w1[k]);
                    int base = o_loc * 36 + j0 + half * 8;
                    *(uint4*)&bs[base]     = make_uint4(hw[0], hw[1], hw[2], hw[3]);
                    *(uint4*)&bs[base + 4] = make_uint4(hw[4], hw[5], hw[6], hw[7]);
                }
            }
            __syncthreads();
            #pragma unroll
            for (int h = 0; h < 2; ++h) {
                FragU a0, a1;
                int g0 = c * 32 + h * 16 + q * 4;
                #pragma unroll
                for (int d = 0; d < 4; ++d) {
                    float kf = (float)(g0 + d + 1);
                    float aa0 = zu0 * kf, aa1 = zu1 * kf;
                    a0.u[d] = pack_trunc2(__cosf(aa0), __sinf(aa0));
                    a1.u[d] = pack_trunc2(__cosf(aa1), __sinf(aa1));
                }
                #pragma unroll
                for (int un = 0; un < 7; ++un) {
                    int row = un * 16 + col;
                    FragU bh;
                    bh.q = *(const uint4*)&bs[row * 36 + h * 16 + q * 4];
                    acc[0][un] = __builtin_amdgcn_mfma_f32_16x16x32_bf16(a0.v, bh.v, acc[0][un], 0, 0, 0);
                    acc[1][un] = __builtin_amdgcn_mfma_f32_16x16x32_bf16(a1.v, bh.v, acc[1][un], 0, 0, 0);
                }
            }
        }
    }
    #pragma unroll
    for (int um = 0; um < 2; ++um) {
        int mbase = mt * 128 + wv * 32 + um * 16 + q * 4;
        #pragma unroll
        for (int un = 0; un < 7; ++un) {
            int o = nt * 112 + un * 16 + col;
            #pragma unroll
            for (int r = 0; r < 4; ++r)
                part2[((size_t)ks * 2048 + mbase + r) * 224 + o] = acc[um][un][r];
        }
    }
}

// ---------------- reduce ks2 planes + fc2_bias -> out[b][o][c] ----------------
__global__ void reduce2_kernel(const float* __restrict__ part2, const float* __restrict__ bias,
                               float* __restrict__ out, int KS) {
    int ot = blockIdx.x;         // 0..12 (o tile of 16)
    int b  = blockIdx.y;         // 0..7
    int t  = threadIdx.x;        // c = 0..255
    float s[16] = {};
    for (int ks = 0; ks < KS; ++ks) {
        const float* p = part2 + ((size_t)ks * 2048 + b * 256 + t) * 224 + ot * 16;
        #pragma unroll
        for (int j4 = 0; j4 < 4; ++j4) {
            float4 a = *(const float4*)(p + j4 * 4);
            s[j4 * 4 + 0] += a.x; s[j4 * 4 + 1] += a.y;
            s[j4 * 4 + 2] += a.z; s[j4 * 4 + 3] += a.w;
        }
    }
    #pragma unroll
    for (int j = 0; j < 16; ++j) {
        int o = ot * 16 + j;
        if (o < 196)
            out[((size_t)b * 196 + o) * 256 + t] = s[j] + bias[o];
    }
}

extern "C" void kernel_launch(void* const* d_in, const int* in_sizes, int n_in,
                              void* d_out, int out_size, void* d_ws, size_t ws_size,
                              hipStream_t stream) {
    const float* x       = (const float*)d_in[0];   // [8,196,128]
    const float* ln1w    = (const float*)d_in[1];
    const float* ln1b    = (const float*)d_in[2];
    const float* fc1c    = (const float*)d_in[3];   // [2,256,128,300]
    const float* fc1bias = (const float*)d_in[4];   // [1,256]
    const float* ln2w    = (const float*)d_in[5];
    const float* ln2b    = (const float*)d_in[6];
    const float* fc2c    = (const float*)d_in[7];   // [2,196,196,300]
    const float* fc2bias = (const float*)d_in[8];   // [1,196]
    float* out = (float*)d_out;                     // [8,196,256] flat

    // workspace layout (floats)
    const size_t xnT_elems = (size_t)128 * 1792;    // 229376
    const size_t h1n_elems = 401408;
    const size_t plane     = 458752;                // 1792*256 == 2048*224
    const size_t fixedB    = (xnT_elems + h1n_elems) * 4;

    int ks1 = 16, ks2 = 14;
    {
        long long planes = (ws_size > fixedB) ? (long long)((ws_size - fixedB) / (plane * 4)) : 2;
        if (planes < 2) planes = 2;
        if (planes < 30) {
            ks1 = (int)(planes / 2);
            ks2 = (int)(planes - ks1);
            if (ks1 < 1) ks1 = 1;
            if (ks2 < 1) ks2 = 1;
            if (ks1 > 16) ks1 = 16;
            if (ks2 > 14) ks2 = 14;
        }
    }

    float* xnT   = (float*)d_ws;
    float* h1n   = xnT + xnT_elems;
    float* part1 = h1n + h1n_elems;
    float* part2 = part1 + (size_t)ks1 * plane;

    ln1_kernel<<<1568, 64, 0, stream>>>(x, ln1w, ln1b, xnT);
    fc1_kernel<<<dim3(2, 14, ks1), 256, 0, stream>>>(xnT, fc1c, part1, ks1);
    reduce1_ln2<<<1568, 256, 0, stream>>>(part1, fc1bias, ln2w, ln2b, h1n, ks1);
    fc2_kernel<<<dim3(2, 16, ks2), 256, 0, stream>>>(h1n, fc2c, part2, ks2);
    reduce2_kernel<<<dim3(13, 8), 256, 0, stream>>>(part2, fc2bias, out, ks2);
}